// Round 2
// 909.316 us; speedup vs baseline: 1.1972x; 1.1972x over previous
//
#include <hip/hip_runtime.h>

#define TOKENS 8192
#define KDIM   4096
#define OUTF   11008
#define NTILE  64            // 4096 / 64-byte K-tiles

typedef int int4v __attribute__((ext_vector_type(4)));

// ---------------- kernel 1: per-token dynamic asymmetric int8 quant ----------------
__global__ __launch_bounds__(256) void quant_x_kernel(
    const float* __restrict__ x, char* __restrict__ q8,
    float* __restrict__ sc, float* __restrict__ zpv, int* __restrict__ qsum)
{
    const int t = blockIdx.x;
    const int tid = threadIdx.x;
    const float4* xr = (const float4*)(x + (size_t)t * KDIM);

    float4 v[4];
    float mn = 3.0e38f, mx = -3.0e38f;
#pragma unroll
    for (int j = 0; j < 4; ++j) {
        v[j] = xr[tid + 256 * j];
        mn = fminf(mn, fminf(fminf(v[j].x, v[j].y), fminf(v[j].z, v[j].w)));
        mx = fmaxf(mx, fmaxf(fmaxf(v[j].x, v[j].y), fmaxf(v[j].z, v[j].w)));
    }
#pragma unroll
    for (int off = 32; off > 0; off >>= 1) {
        mn = fminf(mn, __shfl_down(mn, off, 64));
        mx = fmaxf(mx, __shfl_down(mx, off, 64));
    }
    __shared__ float smn[4], smx[4];
    __shared__ int ssum[4];
    if ((tid & 63) == 0) { smn[tid >> 6] = mn; smx[tid >> 6] = mx; }
    __syncthreads();
    mn = fminf(fminf(smn[0], smn[1]), fminf(smn[2], smn[3]));
    mx = fmaxf(fmaxf(smx[0], smx[1]), fmaxf(smx[2], smx[3]));

    const float min_neg = fminf(mn, 0.0f);
    const float max_pos = fmaxf(mx, 0.0f);
    float scale = (max_pos - min_neg) / 255.0f;
    scale = fmaxf(scale, 1.1920928955078125e-07f);  // FLT_EPSILON
    const float dmin = min_neg / scale;
    const float dmax = max_pos / scale;
    float zpf = ((-128.0f + dmin) + (127.0f + dmax) > 0.0f) ? (-128.0f - dmin)
                                                            : (127.0f - dmax);
    zpf = fminf(fmaxf(rintf(zpf), -128.0f), 127.0f);
    const float inv = 1.0f / scale;

    int s = 0;
    int* qrow = (int*)(q8 + (size_t)t * KDIM);
#pragma unroll
    for (int j = 0; j < 4; ++j) {
        int q0 = (int)fminf(fmaxf(rintf(v[j].x * inv) + zpf, -128.0f), 127.0f);
        int q1 = (int)fminf(fmaxf(rintf(v[j].y * inv) + zpf, -128.0f), 127.0f);
        int q2 = (int)fminf(fmaxf(rintf(v[j].z * inv) + zpf, -128.0f), 127.0f);
        int q3 = (int)fminf(fmaxf(rintf(v[j].w * inv) + zpf, -128.0f), 127.0f);
        s += q0 + q1 + q2 + q3;
        qrow[tid + 256 * j] = (q0 & 255) | ((q1 & 255) << 8) | ((q2 & 255) << 16) | (q3 << 24);
    }
#pragma unroll
    for (int off = 32; off > 0; off >>= 1) s += __shfl_down(s, off, 64);
    if ((tid & 63) == 0) ssum[tid >> 6] = s;
    __syncthreads();
    if (tid == 0) {
        sc[t] = scale;
        zpv[t] = zpf;
        qsum[t] = ssum[0] + ssum[1] + ssum[2] + ssum[3];
    }
}

// ---------------- kernel 2: repack int32 weight -> int8 + row sums ----------------
__global__ __launch_bounds__(256) void pack_w_kernel(
    const int* __restrict__ w, char* __restrict__ w8, int* __restrict__ wsum)
{
    const int o = blockIdx.x;
    const int tid = threadIdx.x;
    const int4* wr = (const int4*)(w + (size_t)o * KDIM);
    int* dst = (int*)(w8 + (size_t)o * KDIM);
    int s = 0;
#pragma unroll
    for (int j = 0; j < 4; ++j) {
        int4 a = wr[tid + 256 * j];
        s += a.x + a.y + a.z + a.w;
        dst[tid + 256 * j] = (a.x & 255) | ((a.y & 255) << 8) | ((a.z & 255) << 16) | (a.w << 24);
    }
#pragma unroll
    for (int off = 32; off > 0; off >>= 1) s += __shfl_down(s, off, 64);
    __shared__ int ss[4];
    if ((tid & 63) == 0) ss[tid >> 6] = s;
    __syncthreads();
    if (tid == 0) wsum[o] = ss[0] + ss[1] + ss[2] + ss[3];
}

// ---------------- kernel 3: int8 GEMM, 256x256 tile, ring-4 deep pipeline ----------------
// BK = 64 int8 (64 B/row). LDS: 4 ring slots x (A 16 KB + B 16 KB) = 128 KB.
// Pipeline: prefetch depth 3, counted s_waitcnt vmcnt(8) (never 0 in main loop),
// ONE raw s_barrier per K-tile (no __syncthreads -> no implicit vmcnt(0) drain).
// vmcnt accounting (per wave): each STAGE = 4 global_load_lds; prologue = 12
// outstanding; vmcnt(8) waits exactly for the 4 loads of the tile about to be
// computed (FIFO). Wait is BEFORE the barrier, so after the barrier ALL waves'
// loads for tile t have landed. Slot (t+3)&3 == (t-1)&3 was fully read before
// every wave's barrier arrival -> no WAR race.
// HARDENING vs previous attempt: __builtin_amdgcn_s_barrier() is NOT a compiler
// memory fence; sched_barrier(0) immediately after it pins the following
// ds_reads/MFMAs below the barrier (rule #18 analog), closing the only
// reordering hole in the schedule. Zero runtime cost.
// LDS swizzle: 16 B chunk c of row r lives at slot c ^ ((r>>1)&3); applied by
// permuting the GLOBAL source column (global_load_lds dest must stay linear,
// rule #21). Read side: coff = (kq ^ ((lr>>1)&3))<<4 -> every 16-lane phase
// spans all 32 banks at 2-way aliasing (free per m136).
__device__ __forceinline__ void async_cp16(const void* g, void* l) {
    __builtin_amdgcn_global_load_lds(
        (const __attribute__((address_space(1))) void*)g,
        (__attribute__((address_space(3))) void*)l, 16, 0, 0);
}

#define STAGE(T)                                                                \
    do {                                                                        \
        char* dA_ = smem + ((T) & 3) * 32768;                                   \
        char* dB_ = dA_ + 16384;                                                \
        const int k0_ = (T) * 64;                                               \
        _Pragma("unroll")                                                       \
        for (int it_ = 0; it_ < 2; ++it_) {                                     \
            const int idx_ = it_ * 512 + tid;                                   \
            const int r_ = idx_ >> 2;                                           \
            const int cs_ = (((idx_ & 3) ^ ((r_ >> 1) & 3)) << 4);              \
            async_cp16(Ag + (size_t)r_ * KDIM + k0_ + cs_, dA_ + idx_ * 16);    \
            async_cp16(Bg + (size_t)r_ * KDIM + k0_ + cs_, dB_ + idx_ * 16);    \
        }                                                                       \
    } while (0)

#define COMPUTE(T)                                                              \
    do {                                                                        \
        const char* sA_ = smem + ((T) & 3) * 32768;                             \
        const char* sB_ = sA_ + 16384;                                          \
        int4v a_[8], b_[4];                                                     \
        _Pragma("unroll")                                                       \
        for (int mi_ = 0; mi_ < 8; ++mi_)                                       \
            a_[mi_] = *(const int4v*)(sA_ + (wm + mi_ * 16 + lr) * 64 + coff);  \
        _Pragma("unroll")                                                       \
        for (int ni_ = 0; ni_ < 4; ++ni_)                                       \
            b_[ni_] = *(const int4v*)(sB_ + (wn + ni_ * 16 + lr) * 64 + coff);  \
        __builtin_amdgcn_s_setprio(1);                                          \
        _Pragma("unroll")                                                       \
        for (int mi_ = 0; mi_ < 8; ++mi_)                                       \
            _Pragma("unroll")                                                   \
            for (int ni_ = 0; ni_ < 4; ++ni_)                                   \
                acc[mi_][ni_] = __builtin_amdgcn_mfma_i32_16x16x64_i8(          \
                    a_[mi_], b_[ni_], acc[mi_][ni_], 0, 0, 0);                  \
        __builtin_amdgcn_s_setprio(0);                                          \
    } while (0)

#define WAIT_BAR(N)                                                             \
    asm volatile("s_waitcnt vmcnt(" #N ")" ::: "memory");                       \
    __builtin_amdgcn_s_barrier();                                               \
    __builtin_amdgcn_sched_barrier(0);

__global__ __launch_bounds__(512, 2) void gemm_i8_kernel(
    const char* __restrict__ q8, const char* __restrict__ w8,
    const float* __restrict__ sc, const float* __restrict__ zpv,
    const int* __restrict__ qsum,
    const float* __restrict__ scales, const float* __restrict__ zeros,
    const int* __restrict__ wsum, float* __restrict__ out)
{
    const int tid = threadIdx.x;
    const int wave = tid >> 6;
    const int lane = tid & 63;

    // T1: XCD-aware swizzle. 1376 blocks % 8 == 0 -> simple bijective remap.
    // Each XCD chunk (172 blocks) = exactly 4 A-panels (4 MB) = one XCD L2.
    const int bid = blockIdx.x;
    const int swz = (bid & 7) * 172 + (bid >> 3);
    const int by = swz / 43;            // M tile 0..31
    const int bx = swz - by * 43;       // N tile 0..42
    const int t0 = by * 256;
    const int o0 = bx * 256;

    __shared__ char smem[131072];       // 4 slots x 32 KB

    const char* Ag = q8 + (size_t)t0 * KDIM;
    const char* Bg = w8 + (size_t)o0 * KDIM;

    const int wm = (wave >> 2) * 128;   // 2 wave-rows of 128
    const int wn = (wave & 3) * 64;     // 4 wave-cols of 64
    const int lr = lane & 15;
    const int kq = lane >> 4;                       // 16B chunk of the 64B K-slice
    const int coff = ((kq ^ ((lr >> 1) & 3)) << 4); // swizzled LDS chunk (lane-const)

    int4v acc[8][4];
#pragma unroll
    for (int mi = 0; mi < 8; ++mi)
#pragma unroll
        for (int ni = 0; ni < 4; ++ni)
            acc[mi][ni] = (int4v){0, 0, 0, 0};

    // prologue: fill pipeline with tiles 0,1,2 (12 loads/wave in flight)
    STAGE(0); STAGE(1); STAGE(2);

    // main loop: wait leaves tiles t+1,t+2 in flight (vmcnt 8)
    for (int t = 0; t < NTILE - 3; ++t) {
        WAIT_BAR(8)
        STAGE(t + 3);
        COMPUTE(t);
    }
    // tail: drain 8 -> 4 -> 0
    WAIT_BAR(8)
    COMPUTE(NTILE - 3);
    WAIT_BAR(4)
    COMPUTE(NTILE - 2);
    WAIT_BAR(0)
    COMPUTE(NTILE - 1);

    // epilogue: out[t,o] = st*so*( dot - zp_t*Wsum_o - z_o*(Qsum_t - 4096*zp_t) )
#pragma unroll
    for (int mi = 0; mi < 8; ++mi) {
        const int tb = t0 + wm + mi * 16 + (kq << 2);
        float st4[4], zp4[4], qs4[4];
        int zi4[4];
#pragma unroll
        for (int r = 0; r < 4; ++r) {
            st4[r] = sc[tb + r];
            zp4[r] = zpv[tb + r];
            zi4[r] = (int)zp4[r];
            qs4[r] = (float)qsum[tb + r];
        }
#pragma unroll
        for (int ni = 0; ni < 4; ++ni) {
            const int o = o0 + wn + ni * 16 + lr;
            const float so = scales[o];
            const float zo = zeros[o];
            const long long wso = (long long)wsum[o];
#pragma unroll
            for (int r = 0; r < 4; ++r) {
                long long iv = (long long)acc[mi][ni][r] - (long long)zi4[r] * wso;
                float val = (float)iv - zo * (qs4[r] - 4096.0f * zp4[r]);
                out[(size_t)(tb + r) * OUTF + o] = st4[r] * so * val;
            }
        }
    }
}

// ---------------- launch ----------------
extern "C" void kernel_launch(void* const* d_in, const int* in_sizes, int n_in,
                              void* d_out, int out_size, void* d_ws, size_t ws_size,
                              hipStream_t stream) {
    const float* x      = (const float*)d_in[0];
    const int*   w      = (const int*)d_in[1];
    const float* scales = (const float*)d_in[2];
    const float* zeros  = (const float*)d_in[3];
    float* out = (float*)d_out;

    char* ws = (char*)d_ws;
    char*  q8   = ws;                              // 33554432 B
    char*  w8   = ws + 33554432;                   // 45088768 B
    float* sc   = (float*)(ws + 78643200);
    float* zp   = (float*)(ws + 78675968);
    int*   qsum = (int*)(ws + 78708736);
    int*   wsum = (int*)(ws + 78741504);

    quant_x_kernel<<<TOKENS, 256, 0, stream>>>(x, q8, sc, zp, qsum);
    pack_w_kernel<<<OUTF, 256, 0, stream>>>(w, w8, wsum);
    gemm_i8_kernel<<<dim3(1376), 512, 0, stream>>>(q8, w8, sc, zp, qsum, scales, zeros, wsum, out);
}